// Round 8
// baseline (88.455 us; speedup 1.0000x reference)
//
#include <hip/hip_runtime.h>
#include <hip/hip_bf16.h>
#include <math.h>

#define BB 4
#define CC 256
#define HH 128
#define WW 128
#define NN (HH*WW)
#define DD 32

// AOT: attention output, bf16, spatially padded +1 border, ci padded 32->44.
#define AOT_CI   44
#define AOT_ROWE (130*AOT_CI)                  // shorts per padded row (5720)
#define AOT_IMGE (130*AOT_ROWE)                // shorts per batch (743600)
#define AOT_BYTES ((size_t)BB*AOT_IMGE*2)      // 5,948,800
#define AOT_ALLOC (AOT_BYTES + 1024)

#define WT_BYTES (9*256*AOT_CI*2)              // 202,752

// conv LDS geometry (2-row tile)
#define PATCH_SZ 45760                         // 4 padded rows * 130 * 88
#define WSLAB    22528                         // 256 co * 88
#define CONV_LDS (PATCH_SZ + 2*WSLAB)          // 90,816
#define EPI_PITCH 260

// qkv: A pre-swizzled [32 kstep][3 cf][64 lane][8 bf16] = 96 KB (L2-resident)
#define ASWZ_BYTES 98304

typedef __attribute__((ext_vector_type(8)))  short bf16x8;
typedef __attribute__((ext_vector_type(4)))  float f32x4;
typedef __attribute__((ext_vector_type(16))) float f32x16;

__device__ inline void async_copy16(void* lds, const void* g) {
    __builtin_amdgcn_global_load_lds(
        (const __attribute__((address_space(1))) unsigned int*)g,
        (__attribute__((address_space(3))) unsigned int*)lds, 16, 0, 0);
}

__device__ inline unsigned short f2bf(float f) {
    __hip_bfloat16 h = __float2bfloat16(f);
    return *reinterpret_cast<unsigned short*>(&h);
}

__device__ inline void split2(float v, unsigned short& h, unsigned short& l) {
    __hip_bfloat16 hb = __float2bfloat16(v);
    float r = v - __bfloat162float(hb);     // exact (Sterbenz)
    __hip_bfloat16 lb = __float2bfloat16(r);
    h = *reinterpret_cast<unsigned short*>(&hb);
    l = *reinterpret_cast<unsigned short*>(&lb);
}

// 8B+8B LDS load of a bf16x8 fragment (88B row pitch is only 8B-aligned)
__device__ inline bf16x8 ld_frag8(const char* p) {
    union { bf16x8 v; short4 h[2]; } u;
    u.h[0] = *(const short4*)(p);
    u.h[1] = *(const short4*)(p + 8);
    return u.v;
}

// A&S 7.1.26 erf approximation, |err| ~1e-6
__device__ inline float gelu_fast(float v) {
    float a = fabsf(v) * 0.70710678118654752f;
    float t = __fdividef(1.0f, fmaf(0.3275911f, a, 1.0f));
    float p = t * fmaf(t, fmaf(t, fmaf(t, fmaf(t, 1.061405429f, -1.453152027f),
                                       1.421413741f), -0.284496736f), 0.254829592f);
    float e = 1.0f - p * __expf(-a * a);
    float erfv = (v < 0.0f) ? -e : e;
    return 0.5f * v * (1.0f + erfv);
}

// ---------------------------------------------------------------------------
// K0: fused prep — conv weight repack | qkv A-pack | AOT border zero.
// ---------------------------------------------------------------------------
__global__ __launch_bounds__(256) void prep_kernel(
    const float* __restrict__ wp, unsigned short* __restrict__ Wt,
    const float* __restrict__ wq, const float* __restrict__ wk,
    const float* __restrict__ wv, unsigned short* __restrict__ Aswz,
    unsigned short* __restrict__ AOT)
{
    const int blk = blockIdx.x;
    if (blk < 288) {                       // conv weights: 9*256*32 = 73728
        int i = blk*256 + threadIdx.x;
        int kk = i / (256*32);
        int r  = i % (256*32);
        int co = r >> 5, ci = r & 31;
        float v = wp[((size_t)co*32 + ci)*9 + kk];
        Wt[((size_t)kk*256 + co)*AOT_CI + ci] = f2bf(v);
    } else if (blk < 480) {                // qkv A image: 49152 entries
        int i = (blk-288)*256 + threadIdx.x;
        int j    = i & 7;
        int lane = (i >> 3) & 63;
        int cf   = (i >> 9) % 3;
        int s    = i / 1536;
        int row  = cf*32 + (lane & 31);
        int k    = s*16 + (lane >> 5)*8 + j;
        int c    = k >> 1;
        float w  = (row < 32) ? wq[row*256 + c]
                 : (row < 64) ? wk[(row-32)*256 + c]
                              : wv[(row-64)*256 + c];
        unsigned short h, l;
        split2(w, h, l);
        Aswz[i] = (k & 1) ? l : h;
    } else {                               // AOT border zero: 4*22704 shorts
        int idx = (blk-480)*256 + threadIdx.x;
        if (idx < BB*22704) {
            int b = idx / 22704;
            int r = idx % 22704;
            size_t off;
            if (r < 11440) {
                int row = (r < 5720) ? 0 : 129;
                int e   = (r < 5720) ? r : r - 5720;
                off = (size_t)b*AOT_IMGE + (size_t)row*AOT_ROWE + e;
            } else {
                int r2 = r - 11440;
                int rr = r2 / 88 + 1;
                int w2 = r2 % 88;
                int col = (w2 < 44) ? 0 : 129;
                int ci  = (w2 < 44) ? w2 : w2 - 44;
                off = (size_t)b*AOT_IMGE + (size_t)rr*AOT_ROWE
                    + (size_t)col*AOT_CI + ci;
            }
            AOT[off] = 0;
        }
    }
}

// ---------------------------------------------------------------------------
// K1: QKV streaming MFMA GEMM — 1-wave blocks, no LDS, no barriers.
// grid (512 n-tiles, B), 64 thr.  Wave owns 32 n.  A-fragments read directly
// from global (L2-resident, coalesced 1KB/inst, depth-2 reg queue); x via
// depth-8 reg queue (32 dwords in flight).  Truncation-split to (hi,lo);
// MFMA 32x32x16: acc += A*(xh dup) + A*(xl dup)  (A k-slots = [w_hi, w_lo]).
// Epilogue: Q,K,V (+bias) -> QKV[b][96][N] global (fp32).
// ---------------------------------------------------------------------------
__global__ __launch_bounds__(64) void qkv_mfma_kernel(
    const float* __restrict__ x, const unsigned short* __restrict__ Aswz,
    const float* __restrict__ bq, const float* __restrict__ bk,
    const float* __restrict__ bv, float* __restrict__ QKV)
{
    const int b    = blockIdx.y;
    const int s    = blockIdx.x;                 // 0..511
    const int n0   = s * 32;
    const int lane = threadIdx.x;
    const int l31  = lane & 31;
    const int lh   = lane >> 5;

    const float* xlane = x + ((size_t)b*CC + 4*lh)*NN + (n0 + l31);
    const bf16x8* Ab = (const bf16x8*)Aswz;      // frag id: (st*3+cf)*64+lane

    f32x16 acc0 = {0}, acc1 = {0}, acc2 = {0};

    // x prefetch queue: depth 8 slots x 4 dwords
    float xq[8][4];
    #pragma unroll
    for (int p0 = 0; p0 < 8; ++p0) {
        const float* p = xlane + (size_t)(8*p0)*NN;
        xq[p0][0] = p[0];            xq[p0][1] = p[(size_t)NN];
        xq[p0][2] = p[(size_t)2*NN]; xq[p0][3] = p[(size_t)3*NN];
    }
    // A prefetch queue: depth 2 steps x 3 frags
    bf16x8 aq[2][3];
    #pragma unroll
    for (int p0 = 0; p0 < 2; ++p0) {
        aq[p0][0] = Ab[(p0*3 + 0)*64 + lane];
        aq[p0][1] = Ab[(p0*3 + 1)*64 + lane];
        aq[p0][2] = Ab[(p0*3 + 2)*64 + lane];
    }

    for (int g = 0; g < 4; ++g) {
        #pragma unroll
        for (int ph = 0; ph < 8; ++ph) {
            const int st = g*8 + ph;
            bf16x8 a0 = aq[ph & 1][0];
            bf16x8 a1 = aq[ph & 1][1];
            bf16x8 a2 = aq[ph & 1][2];
            if (st + 2 < 32) {
                aq[ph & 1][0] = Ab[((st+2)*3 + 0)*64 + lane];
                aq[ph & 1][1] = Ab[((st+2)*3 + 1)*64 + lane];
                aq[ph & 1][2] = Ab[((st+2)*3 + 2)*64 + lane];
            }
            float v0 = xq[ph][0], v1 = xq[ph][1];
            float v2 = xq[ph][2], v3 = xq[ph][3];
            if (st + 8 < 32) {
                const float* p = xlane + (size_t)(8*(st+8))*NN;
                xq[ph][0] = p[0];            xq[ph][1] = p[(size_t)NN];
                xq[ph][2] = p[(size_t)2*NN]; xq[ph][3] = p[(size_t)3*NN];
            }
            // truncation split: hi = bits&0xFFFF0000, lo = trunc16(v-hi)
            union { bf16x8 v; unsigned int u[4]; } B1, B2;
            #pragma unroll
            for (int j = 0; j < 4; ++j) {
                float vj = (j==0)?v0:(j==1)?v1:(j==2)?v2:v3;
                unsigned int hb = __float_as_uint(vj) & 0xFFFF0000u;
                float rj = vj - __uint_as_float(hb);
                unsigned int lb = __float_as_uint(rj) >> 16;
                B1.u[j] = hb | (hb >> 16);
                B2.u[j] = lb | (lb << 16);
            }
            acc0 = __builtin_amdgcn_mfma_f32_32x32x16_bf16(a0, B1.v, acc0, 0, 0, 0);
            acc1 = __builtin_amdgcn_mfma_f32_32x32x16_bf16(a1, B1.v, acc1, 0, 0, 0);
            acc2 = __builtin_amdgcn_mfma_f32_32x32x16_bf16(a2, B1.v, acc2, 0, 0, 0);
            acc0 = __builtin_amdgcn_mfma_f32_32x32x16_bf16(a0, B2.v, acc0, 0, 0, 0);
            acc1 = __builtin_amdgcn_mfma_f32_32x32x16_bf16(a1, B2.v, acc1, 0, 0, 0);
            acc2 = __builtin_amdgcn_mfma_f32_32x32x16_bf16(a2, B2.v, acc2, 0, 0, 0);
        }
    }

    // epilogue: bias + stores.  bias float4 q covers rows 8q+4lh+{0..3},
    // matching acc reg r = 4q+j -> rsub = j + 8q + 4lh.
    float4 bq4[4], bk4[4], bv4[4];
    #pragma unroll
    for (int q = 0; q < 4; ++q) {
        bq4[q] = *(const float4*)(bq + 8*q + 4*lh);
        bk4[q] = *(const float4*)(bk + 8*q + 4*lh);
        bv4[q] = *(const float4*)(bv + 8*q + 4*lh);
    }
    float* Qo = QKV + (size_t)b*96*NN + n0 + l31;
    #pragma unroll
    for (int r = 0; r < 16; ++r) {
        const int q = r >> 2, j = r & 3;
        const int rsub = j + 8*q + 4*lh;
        const float bqv = (j==0)?bq4[q].x:(j==1)?bq4[q].y:(j==2)?bq4[q].z:bq4[q].w;
        const float bkv = (j==0)?bk4[q].x:(j==1)?bk4[q].y:(j==2)?bk4[q].z:bk4[q].w;
        const float bvv = (j==0)?bv4[q].x:(j==1)?bv4[q].y:(j==2)?bv4[q].z:bv4[q].w;
        Qo[(size_t)(rsub     )*NN] = acc0[r] + bqv;
        Qo[(size_t)(rsub + 32)*NN] = acc1[r] + bkv;
        Qo[(size_t)(rsub + 64)*NN] = acc2[r] + bvv;
    }
}

// ---------------------------------------------------------------------------
// K2: energy partials.  E[d][e] = sum_n Q[d][n]*K[e][n], fp32, 4x4 reg tile.
// grid (64 chunks of 256 n, B), 256 thr = (4 n-subs x 64 tiles).
// Block-local ns-reduction in LDS -> Ep[s][b][1024]  (64 partial sets).
// ---------------------------------------------------------------------------
__global__ __launch_bounds__(256) void energy_kernel(
    const float* __restrict__ QKV, float* __restrict__ Ep)
{
    __shared__ float Es[4][1024];
    const int b  = blockIdx.y;
    const int s  = blockIdx.x;
    const int t  = threadIdx.x;
    const int ns = t >> 6;
    const int tt = t & 63;
    const int d0 = ((tt >> 3) & 7) * 4;
    const int e0 = (tt & 7) * 4;
    const int n1 = s*256 + ns*64;
    const float* Qb = QKV + (size_t)b*96*NN;

    float acc[4][4] = {};
    #pragma unroll 4
    for (int it = 0; it < 16; ++it) {
        const int nn = n1 + it*4;
        float4 q4[4], k4[4];
        #pragma unroll
        for (int i = 0; i < 4; ++i) {
            q4[i] = *(const float4*)(Qb + (size_t)(d0 + i)*NN + nn);
            k4[i] = *(const float4*)(Qb + (size_t)(32 + e0 + i)*NN + nn);
        }
        #pragma unroll
        for (int i = 0; i < 4; ++i)
            #pragma unroll
            for (int j = 0; j < 4; ++j)
                acc[i][j] += q4[i].x*k4[j].x + q4[i].y*k4[j].y
                           + q4[i].z*k4[j].z + q4[i].w*k4[j].w;
    }
    #pragma unroll
    for (int i = 0; i < 4; ++i)
        #pragma unroll
        for (int j = 0; j < 4; ++j)
            Es[ns][(d0 + i)*32 + e0 + j] = acc[i][j];
    __syncthreads();
    for (int i = t; i < 1024; i += 256)
        Ep[((size_t)s*BB + b)*1024 + i] = Es[0][i] + Es[1][i] + Es[2][i] + Es[3][i];
}

// ---------------------------------------------------------------------------
// K3: softmax over 64 partials.  softmax(max-E)==softmax(-E).
// ---------------------------------------------------------------------------
__global__ __launch_bounds__(1024) void softmax_kernel(
    const float* __restrict__ Ep, float* __restrict__ attT)
{
    const int b = blockIdx.x;
    const int e = threadIdx.x, d = threadIdx.y;
    float s = 0.f;
    for (int p = 0; p < 64; ++p)
        s += Ep[((size_t)p * BB + b) * (DD * DD) + d * DD + e];
    float nv = -s;
    float m = nv;
    for (int off = 16; off > 0; off >>= 1) m = fmaxf(m, __shfl_xor(m, off, 32));
    float pe = expf(nv - m);
    float su = pe;
    for (int off = 16; off > 0; off >>= 1) su += __shfl_xor(su, off, 32);
    attT[(size_t)b * (DD * DD) + e * DD + d] = pe / su;
}

// ---------------------------------------------------------------------------
// K4: PV — reads V = QKV rows 64..95; writes bf16 AOT padded layout.
// ---------------------------------------------------------------------------
__global__ __launch_bounds__(256) void pv_kernel(
    const float* __restrict__ QKV, const float* __restrict__ attT,
    unsigned short* __restrict__ AOT)
{
    __shared__ float Vs[DD][128];
    __shared__ float at4[DD][DD];        // [e][d]
    const int b  = blockIdx.y;
    const int n0 = blockIdx.x * 128;
    const int tid = threadIdx.x;
    for (int i = tid; i < 1024; i += 256) {
        int r = i >> 5, c4 = i & 31;
        *(float4*)&Vs[r][c4*4] =
            *(const float4*)(QKV + ((size_t)b*96 + 64 + r)*NN + n0 + c4*4);
    }
    for (int i = tid; i < 1024; i += 256)
        at4[i >> 5][i & 31] = attT[(size_t)b*1024 + i];
    __syncthreads();
    const int nl = tid & 127;
    const int dg = tid >> 7;
    float acc[16];
    #pragma unroll
    for (int k = 0; k < 16; ++k) acc[k] = 0.f;
    #pragma unroll 4
    for (int e = 0; e < DD; ++e) {
        float v = Vs[e][nl];
        const float4* ar = (const float4*)&at4[e][dg*16];
        #pragma unroll
        for (int q = 0; q < 4; ++q) {
            float4 a = ar[q];
            acc[4*q+0] += a.x * v; acc[4*q+1] += a.y * v;
            acc[4*q+2] += a.z * v; acc[4*q+3] += a.w * v;
        }
    }
    const int n = n0 + nl;
    const int h = n >> 7, w = n & 127;
    unsigned short* dst = AOT + (size_t)b*AOT_IMGE + (size_t)(h+1)*AOT_ROWE
                              + (size_t)(w+1)*AOT_CI + dg*16;
    #pragma unroll
    for (int q = 0; q < 4; ++q) {
        ushort4 u;
        u.x = f2bf(acc[4*q+0]); u.y = f2bf(acc[4*q+1]);
        u.z = f2bf(acc[4*q+2]); u.w = f2bf(acc[4*q+3]);
        *(ushort4*)(dst + 4*q) = u;
    }
}

// ---------------------------------------------------------------------------
// K5: conv implicit-GEMM, 2 H-rows per block (unchanged).
// ---------------------------------------------------------------------------
__global__ __launch_bounds__(512, 1) void conv_kernel(
    const unsigned short* __restrict__ AOT, const unsigned short* __restrict__ Wt,
    const float* __restrict__ gammap, const float* __restrict__ x,
    float* __restrict__ out)
{
    __shared__ __align__(16) char lds[CONV_LDS];
    const int b   = blockIdx.y;
    const int h0  = blockIdx.x * 2;
    const int tid = threadIdx.x;
    const int wid = tid >> 6;
    const int lane = tid & 63;
    const int l15 = lane & 15;
    const int lj  = lane >> 4;
    const int wn  = wid & 1;
    const int wc  = wid >> 1;

    const char* psrc = (const char*)(AOT + (size_t)b*AOT_IMGE + (size_t)h0*AOT_ROWE);
    for (int i = tid; i < PATCH_SZ/16; i += 512)
        async_copy16(lds + i*16, psrc + i*16);
    for (int i = tid; i < WSLAB/16; i += 512)
        async_copy16(lds + PATCH_SZ + i*16, (const char*)Wt + i*16);
    __syncthreads();

    f32x4 acc[4][8];
    #pragma unroll
    for (int cf = 0; cf < 4; ++cf)
        #pragma unroll
        for (int nf = 0; nf < 8; ++nf)
            acc[cf][nf] = (f32x4){0.f, 0.f, 0.f, 0.f};

    for (int kk = 0; kk < 9; ++kk) {
        if (kk < 8) {
            const char* wsrc = (const char*)Wt + (size_t)(kk+1)*WSLAB;
            char* wdst = lds + PATCH_SZ + ((kk+1)&1)*WSLAB;
            for (int i = tid; i < WSLAB/16; i += 512)
                async_copy16(wdst + i*16, wsrc + i*16);
        }
        const int kh = kk / 3, kw = kk % 3;
        const char* wbase = lds + PATCH_SZ + (kk&1)*WSLAB;
        bf16x8 af[4];
        #pragma unroll
        for (int cf = 0; cf < 4; ++cf)
            af[cf] = ld_frag8(wbase + (wc*64 + cf*16 + l15)*88 + lj*16);
        #pragma unroll
        for (int nf = 0; nf < 8; ++nf) {
            const int cell = (wn + kh)*130 + nf*16 + l15 + kw;
            const bf16x8 bfr = ld_frag8(lds + cell*88 + lj*16);
            #pragma unroll
            for (int cf = 0; cf < 4; ++cf)
                acc[cf][nf] = __builtin_amdgcn_mfma_f32_16x16x32_bf16(
                    af[cf], bfr, acc[cf][nf], 0, 0, 0);
        }
        __syncthreads();
    }

    const float g0 = gammap[0];
    float* lf = (float*)lds;
    for (int k = 0; k < 4; ++k) {
        if (wc == k) {
            #pragma unroll
            for (int cf = 0; cf < 4; ++cf) {
                const int rl = cf*16 + 4*lj;
                #pragma unroll
                for (int nf = 0; nf < 8; ++nf) {
                    const int col = wn*128 + nf*16 + l15;
                    #pragma unroll
                    for (int j = 0; j < 4; ++j)
                        lf[(rl + j)*EPI_PITCH + col] = acc[cf][nf][j];
                }
            }
        }
        __syncthreads();
        #pragma unroll
        for (int it = 0; it < 8; ++it) {
            const int idx = tid + it*512;
            const int row = idx >> 6, c4 = idx & 63;
            const int co  = k*64 + row;
            const size_t g = ((size_t)b*CC + co)*NN + (size_t)h0*WW + c4*4;
            float4 v  = *(const float4*)(lf + row*EPI_PITCH + c4*4);
            float4 xv = *(const float4*)(x + g);
            float4 o;
            o.x = g0*gelu_fast(v.x) + xv.x;
            o.y = g0*gelu_fast(v.y) + xv.y;
            o.z = g0*gelu_fast(v.z) + xv.z;
            o.w = g0*gelu_fast(v.w) + xv.w;
            *(float4*)(out + g) = o;
        }
        __syncthreads();
    }
}

// ---------------------------------------------------------------------------
extern "C" void kernel_launch(void* const* d_in, const int* in_sizes, int n_in,
                              void* d_out, int out_size, void* d_ws, size_t ws_size,
                              hipStream_t stream)
{
    const float* x  = (const float*)d_in[0];
    const float* wq = (const float*)d_in[1];
    const float* bq = (const float*)d_in[2];
    const float* wk = (const float*)d_in[3];
    const float* bk = (const float*)d_in[4];
    const float* wv = (const float*)d_in[5];
    const float* bv = (const float*)d_in[6];
    const float* wp = (const float*)d_in[7];
    const float* gm = (const float*)d_in[8];
    float* out = (float*)d_out;

    // QKV[b][96][N] fp32 aliased into d_out (energy/pv read it; conv
    // overwrites all of d_out last).
    float* QKV = out;

    char* ws = (char*)d_ws;
    unsigned short* AOT  = (unsigned short*)ws;
    unsigned short* Wt   = (unsigned short*)(ws + AOT_ALLOC);
    unsigned short* Aswz = (unsigned short*)(ws + AOT_ALLOC + WT_BYTES);
    float* Ep  = (float*)(ws + AOT_ALLOC + WT_BYTES + ASWZ_BYTES);  // 1 MB
    float* ATT = Ep + (size_t)64*BB*1024;

    prep_kernel    <<<dim3(1024), 256, 0, stream>>>(wp, Wt, wq, wk, wv, Aswz, AOT);
    qkv_mfma_kernel<<<dim3(512, BB), 64, 0, stream>>>(x, Aswz, bq, bk, bv, QKV);
    energy_kernel  <<<dim3(64, BB), 256, 0, stream>>>(QKV, Ep);
    softmax_kernel <<<dim3(BB), dim3(32, 32), 0, stream>>>(Ep, ATT);
    pv_kernel      <<<dim3(128, BB), 256, 0, stream>>>(QKV, ATT, AOT);
    conv_kernel    <<<dim3(64, BB), 512, 0, stream>>>(AOT, Wt, gm, x, out);
}

// Round 9
// 83.371 us; speedup vs baseline: 1.0610x; 1.0610x over previous
//
#include <hip/hip_runtime.h>
#include <hip/hip_bf16.h>
#include <math.h>

#define BB 4
#define CC 256
#define HH 128
#define WW 128
#define NN (HH*WW)
#define DD 32

// AOT: attention output, bf16, spatially padded +1 border, ci padded 32->44.
#define AOT_CI   44
#define AOT_ROWE (130*AOT_CI)                  // shorts per padded row (5720)
#define AOT_IMGE (130*AOT_ROWE)                // shorts per batch (743600)
#define AOT_BYTES ((size_t)BB*AOT_IMGE*2)      // 5,948,800
#define AOT_ALLOC (AOT_BYTES + 1024)

#define WT_BYTES (9*256*AOT_CI*2)              // 202,752

// conv LDS geometry (2-row tile)
#define PATCH_SZ 45760                         // 4 padded rows * 130 * 88
#define WSLAB    22528                         // 256 co * 88
#define CONV_LDS (PATCH_SZ + 2*WSLAB)          // 90,816
#define EPI_PITCH 260

// qkv: A pre-swizzled [32 kstep][3 cf][64 lane][8 bf16] = 96 KB (L2-resident)
#define ASWZ_BYTES 98304
#define QKPITCH 36                             // fused-energy qk row pitch

typedef __attribute__((ext_vector_type(8)))  short bf16x8;
typedef __attribute__((ext_vector_type(4)))  float f32x4;
typedef __attribute__((ext_vector_type(16))) float f32x16;

__device__ inline void async_copy16(void* lds, const void* g) {
    __builtin_amdgcn_global_load_lds(
        (const __attribute__((address_space(1))) unsigned int*)g,
        (__attribute__((address_space(3))) unsigned int*)lds, 16, 0, 0);
}

__device__ inline unsigned short f2bf(float f) {
    __hip_bfloat16 h = __float2bfloat16(f);
    return *reinterpret_cast<unsigned short*>(&h);
}

__device__ inline void split2(float v, unsigned short& h, unsigned short& l) {
    __hip_bfloat16 hb = __float2bfloat16(v);
    float r = v - __bfloat162float(hb);     // exact (Sterbenz)
    __hip_bfloat16 lb = __float2bfloat16(r);
    h = *reinterpret_cast<unsigned short*>(&hb);
    l = *reinterpret_cast<unsigned short*>(&lb);
}

// 8B+8B LDS load of a bf16x8 fragment (88B row pitch is only 8B-aligned)
__device__ inline bf16x8 ld_frag8(const char* p) {
    union { bf16x8 v; short4 h[2]; } u;
    u.h[0] = *(const short4*)(p);
    u.h[1] = *(const short4*)(p + 8);
    return u.v;
}

// A&S 7.1.26 erf approximation, |err| ~1e-6
__device__ inline float gelu_fast(float v) {
    float a = fabsf(v) * 0.70710678118654752f;
    float t = __fdividef(1.0f, fmaf(0.3275911f, a, 1.0f));
    float p = t * fmaf(t, fmaf(t, fmaf(t, fmaf(t, 1.061405429f, -1.453152027f),
                                       1.421413741f), -0.284496736f), 0.254829592f);
    float e = 1.0f - p * __expf(-a * a);
    float erfv = (v < 0.0f) ? -e : e;
    return 0.5f * v * (1.0f + erfv);
}

// ---------------------------------------------------------------------------
// K0: fused prep — conv weight repack | qkv A-pack | AOT border zero.
// ---------------------------------------------------------------------------
__global__ __launch_bounds__(256) void prep_kernel(
    const float* __restrict__ wp, unsigned short* __restrict__ Wt,
    const float* __restrict__ wq, const float* __restrict__ wk,
    const float* __restrict__ wv, unsigned short* __restrict__ Aswz,
    unsigned short* __restrict__ AOT)
{
    const int blk = blockIdx.x;
    if (blk < 288) {                       // conv weights: 9*256*32 = 73728
        int i = blk*256 + threadIdx.x;
        int kk = i / (256*32);
        int r  = i % (256*32);
        int co = r >> 5, ci = r & 31;
        float v = wp[((size_t)co*32 + ci)*9 + kk];
        Wt[((size_t)kk*256 + co)*AOT_CI + ci] = f2bf(v);
    } else if (blk < 480) {                // qkv A image: 49152 entries
        int i = (blk-288)*256 + threadIdx.x;
        int j    = i & 7;
        int lane = (i >> 3) & 63;
        int cf   = (i >> 9) % 3;
        int s    = i / 1536;
        int row  = cf*32 + (lane & 31);
        int k    = s*16 + (lane >> 5)*8 + j;
        int c    = k >> 1;
        float w  = (row < 32) ? wq[row*256 + c]
                 : (row < 64) ? wk[(row-32)*256 + c]
                              : wv[(row-64)*256 + c];
        unsigned short h, l;
        split2(w, h, l);
        Aswz[i] = (k & 1) ? l : h;
    } else {                               // AOT border zero: 4*22704 shorts
        int idx = (blk-480)*256 + threadIdx.x;
        if (idx < BB*22704) {
            int b = idx / 22704;
            int r = idx % 22704;
            size_t off;
            if (r < 11440) {
                int row = (r < 5720) ? 0 : 129;
                int e   = (r < 5720) ? r : r - 5720;
                off = (size_t)b*AOT_IMGE + (size_t)row*AOT_ROWE + e;
            } else {
                int r2 = r - 11440;
                int rr = r2 / 88 + 1;
                int w2 = r2 % 88;
                int col = (w2 < 44) ? 0 : 129;
                int ci  = (w2 < 44) ? w2 : w2 - 44;
                off = (size_t)b*AOT_IMGE + (size_t)rr*AOT_ROWE
                    + (size_t)col*AOT_CI + ci;
            }
            AOT[off] = 0;
        }
    }
}

// ---------------------------------------------------------------------------
// K1: QKV MFMA GEMM, K-split across 4 waves (wave w: channels [64w,64w+64)).
// grid (512 n-tiles of 32, B), 256 thr.  Per wave: 8 k-steps, ALL x loads
// (32 dwords) prefetched upfront; A-frags from global (L2) depth-2 queue.
// Reduce partials via LDS slabs; fused epilogue: Q,K(+bias) -> qk LDS tile
// (pitch 36, conflict-free), V(+bias) -> global, energy partial E[32][32]
// over this block's 32 n -> Ep[s][b] (512 partial sets).
// ---------------------------------------------------------------------------
__global__ __launch_bounds__(256) void qkv_mfma_kernel(
    const float* __restrict__ x, const unsigned short* __restrict__ Aswz,
    const float* __restrict__ bq, const float* __restrict__ bk,
    const float* __restrict__ bv,
    float* __restrict__ Vout, float* __restrict__ Ep)
{
    __shared__ __align__(16) float lds_f[4*3072 + 96];   // slabs + bias
    const int b    = blockIdx.y;
    const int s    = blockIdx.x;                 // 0..511
    const int n0   = s * 32;
    const int tid  = threadIdx.x;
    const int w    = tid >> 6;
    const int lane = tid & 63;
    const int l31  = lane & 31;
    const int lh   = lane >> 5;

    float* biasL = lds_f + 12288;
    if (tid < 96)
        biasL[tid] = (tid < 32) ? bq[tid] : (tid < 64) ? bk[tid-32] : bv[tid-64];

    const float* xlane = x + ((size_t)b*CC + 64*w + 4*lh)*NN + (n0 + l31);
    const bf16x8* Ab = (const bf16x8*)Aswz;
    const int st0 = 8*w;

    // prefetch ALL x for this wave's 8 steps (32 loads in flight)
    float xq[8][4];
    #pragma unroll
    for (int p = 0; p < 8; ++p) {
        const float* pp = xlane + (size_t)(8*p)*NN;
        xq[p][0] = pp[0];            xq[p][1] = pp[(size_t)NN];
        xq[p][2] = pp[(size_t)2*NN]; xq[p][3] = pp[(size_t)3*NN];
    }
    // A-frag queue depth 2
    bf16x8 aq[2][3];
    #pragma unroll
    for (int p = 0; p < 2; ++p) {
        aq[p][0] = Ab[((st0+p)*3 + 0)*64 + lane];
        aq[p][1] = Ab[((st0+p)*3 + 1)*64 + lane];
        aq[p][2] = Ab[((st0+p)*3 + 2)*64 + lane];
    }

    f32x16 acc0 = {0}, acc1 = {0}, acc2 = {0};
    #pragma unroll
    for (int ph = 0; ph < 8; ++ph) {
        bf16x8 a0 = aq[ph & 1][0];
        bf16x8 a1 = aq[ph & 1][1];
        bf16x8 a2 = aq[ph & 1][2];
        if (ph < 6) {
            aq[ph & 1][0] = Ab[((st0+ph+2)*3 + 0)*64 + lane];
            aq[ph & 1][1] = Ab[((st0+ph+2)*3 + 1)*64 + lane];
            aq[ph & 1][2] = Ab[((st0+ph+2)*3 + 2)*64 + lane];
        }
        // truncation split: hi = bits&0xFFFF0000, lo = trunc16(v-hi)
        union { bf16x8 v; unsigned int u[4]; } B1, B2;
        #pragma unroll
        for (int j = 0; j < 4; ++j) {
            float vj = xq[ph][j];
            unsigned int hb = __float_as_uint(vj) & 0xFFFF0000u;
            float rj = vj - __uint_as_float(hb);
            unsigned int lb = __float_as_uint(rj) >> 16;
            B1.u[j] = hb | (hb >> 16);
            B2.u[j] = lb | (lb << 16);
        }
        acc0 = __builtin_amdgcn_mfma_f32_32x32x16_bf16(a0, B1.v, acc0, 0, 0, 0);
        acc1 = __builtin_amdgcn_mfma_f32_32x32x16_bf16(a1, B1.v, acc1, 0, 0, 0);
        acc2 = __builtin_amdgcn_mfma_f32_32x32x16_bf16(a2, B1.v, acc2, 0, 0, 0);
        acc0 = __builtin_amdgcn_mfma_f32_32x32x16_bf16(a0, B2.v, acc0, 0, 0, 0);
        acc1 = __builtin_amdgcn_mfma_f32_32x32x16_bf16(a1, B2.v, acc1, 0, 0, 0);
        acc2 = __builtin_amdgcn_mfma_f32_32x32x16_bf16(a2, B2.v, acc2, 0, 0, 0);
    }

    // ---- phase A: write per-wave partial slabs (2-way banks max) ----
    float* slab = lds_f + w*3072;
    #pragma unroll
    for (int r = 0; r < 16; ++r) {
        slab[(     r)*64 + lane] = acc0[r];
        slab[(16 + r)*64 + lane] = acc1[r];
        slab[(32 + r)*64 + lane] = acc2[r];
    }
    __syncthreads();

    // ---- phase B: reduce 4 partials + bias (into registers) ----
    // acc mapping: row = cf*32 + rsub, rsub = j + 8q + 4lh, reg r = 4q+j,
    // lane = lh*32 + n  (verified r4-r8 epilogues)
    float sums[12];
    #pragma unroll
    for (int i = 0; i < 12; ++i) {
        const int idx = tid + i*256;            // 0..3071
        const int row = idx >> 5, n = idx & 31;
        const int cf = row >> 5, rsub = row & 31;
        const int r   = ((rsub >> 3) << 2) | (rsub & 3);
        const int lh2 = (rsub >> 2) & 1;
        const int fo  = (cf*16 + r)*64 + lh2*32 + n;
        sums[i] = lds_f[fo] + lds_f[3072 + fo] + lds_f[6144 + fo]
                + lds_f[9216 + fo] + biasL[row];
    }
    __syncthreads();

    // ---- phase C: scatter Q,K -> qk tile (reuses slab space), V -> global
    #pragma unroll
    for (int i = 0; i < 12; ++i) {
        const int idx = tid + i*256;
        const int row = idx >> 5, n = idx & 31;
        if (row < 64)
            lds_f[row*QKPITCH + n] = sums[i];
        else
            Vout[((size_t)b*DD + (row-64))*NN + n0 + n] = sums[i];
    }
    __syncthreads();

    // ---- phase D: energy partial E[d][e] = sum_n Q[d][n]*K[e][n] ----
    const int d  = tid >> 3;                    // 0..31
    const int e0 = tid & 7;
    const float* qrow = lds_f + d*QKPITCH;
    float s0 = 0.f, s1 = 0.f, s2 = 0.f, s3 = 0.f;
    #pragma unroll
    for (int n4 = 0; n4 < 32; n4 += 4) {
        float4 qv = *(const float4*)(qrow + n4);
        float4 k0 = *(const float4*)(lds_f + (32 + e0     )*QKPITCH + n4);
        float4 k1 = *(const float4*)(lds_f + (32 + e0 +  8)*QKPITCH + n4);
        float4 k2 = *(const float4*)(lds_f + (32 + e0 + 16)*QKPITCH + n4);
        float4 k3 = *(const float4*)(lds_f + (32 + e0 + 24)*QKPITCH + n4);
        s0 += qv.x*k0.x + qv.y*k0.y + qv.z*k0.z + qv.w*k0.w;
        s1 += qv.x*k1.x + qv.y*k1.y + qv.z*k1.z + qv.w*k1.w;
        s2 += qv.x*k2.x + qv.y*k2.y + qv.z*k2.z + qv.w*k2.w;
        s3 += qv.x*k3.x + qv.y*k3.y + qv.z*k3.z + qv.w*k3.w;
    }
    float* ep = Ep + ((size_t)s*BB + b)*1024;
    ep[d*32 + e0]      = s0;
    ep[d*32 + e0 + 8]  = s1;
    ep[d*32 + e0 + 16] = s2;
    ep[d*32 + e0 + 24] = s3;
}

// ---------------------------------------------------------------------------
// K2: fold 512 energy partials -> 64 (8:1), float4 per thread.
// ---------------------------------------------------------------------------
__global__ __launch_bounds__(256) void ereduce_kernel(
    const float* __restrict__ Ep, float* __restrict__ Epr)
{
    const int b = blockIdx.y, S = blockIdx.x;   // S: 0..63
    const int t = threadIdx.x;
    float4 a = {0.f, 0.f, 0.f, 0.f};
    #pragma unroll
    for (int p = 0; p < 8; ++p) {
        float4 v = *(const float4*)(Ep + ((size_t)(S*8 + p)*BB + b)*1024 + t*4);
        a.x += v.x; a.y += v.y; a.z += v.z; a.w += v.w;
    }
    *(float4*)(Epr + ((size_t)S*BB + b)*1024 + t*4) = a;
}

// ---------------------------------------------------------------------------
// K3: softmax over 64 partials.  softmax(max-E)==softmax(-E).
// ---------------------------------------------------------------------------
__global__ __launch_bounds__(1024) void softmax_kernel(
    const float* __restrict__ Ep, float* __restrict__ attT)
{
    const int b = blockIdx.x;
    const int e = threadIdx.x, d = threadIdx.y;
    float s = 0.f;
    for (int p = 0; p < 64; ++p)
        s += Ep[((size_t)p * BB + b) * (DD * DD) + d * DD + e];
    float nv = -s;
    float m = nv;
    for (int off = 16; off > 0; off >>= 1) m = fmaxf(m, __shfl_xor(m, off, 32));
    float pe = expf(nv - m);
    float su = pe;
    for (int off = 16; off > 0; off >>= 1) su += __shfl_xor(su, off, 32);
    attT[(size_t)b * (DD * DD) + e * DD + d] = pe / su;
}

// ---------------------------------------------------------------------------
// K4: PV — reads standalone V[b][32][N]; writes bf16 AOT padded layout.
// ---------------------------------------------------------------------------
__global__ __launch_bounds__(256) void pv_kernel(
    const float* __restrict__ V, const float* __restrict__ attT,
    unsigned short* __restrict__ AOT)
{
    __shared__ float Vs[DD][128];
    __shared__ float at4[DD][DD];        // [e][d]
    const int b  = blockIdx.y;
    const int n0 = blockIdx.x * 128;
    const int tid = threadIdx.x;
    for (int i = tid; i < 1024; i += 256) {
        int r = i >> 5, c4 = i & 31;
        *(float4*)&Vs[r][c4*4] =
            *(const float4*)(V + ((size_t)b*DD + r)*NN + n0 + c4*4);
    }
    for (int i = tid; i < 1024; i += 256)
        at4[i >> 5][i & 31] = attT[(size_t)b*1024 + i];
    __syncthreads();
    const int nl = tid & 127;
    const int dg = tid >> 7;
    float acc[16];
    #pragma unroll
    for (int k = 0; k < 16; ++k) acc[k] = 0.f;
    #pragma unroll 4
    for (int e = 0; e < DD; ++e) {
        float v = Vs[e][nl];
        const float4* ar = (const float4*)&at4[e][dg*16];
        #pragma unroll
        for (int q = 0; q < 4; ++q) {
            float4 a = ar[q];
            acc[4*q+0] += a.x * v; acc[4*q+1] += a.y * v;
            acc[4*q+2] += a.z * v; acc[4*q+3] += a.w * v;
        }
    }
    const int n = n0 + nl;
    const int h = n >> 7, w = n & 127;
    unsigned short* dst = AOT + (size_t)b*AOT_IMGE + (size_t)(h+1)*AOT_ROWE
                              + (size_t)(w+1)*AOT_CI + dg*16;
    #pragma unroll
    for (int q = 0; q < 4; ++q) {
        ushort4 u;
        u.x = f2bf(acc[4*q+0]); u.y = f2bf(acc[4*q+1]);
        u.z = f2bf(acc[4*q+2]); u.w = f2bf(acc[4*q+3]);
        *(ushort4*)(dst + 4*q) = u;
    }
}

// ---------------------------------------------------------------------------
// K5: conv implicit-GEMM, 2 H-rows per block (unchanged).
// ---------------------------------------------------------------------------
__global__ __launch_bounds__(512, 1) void conv_kernel(
    const unsigned short* __restrict__ AOT, const unsigned short* __restrict__ Wt,
    const float* __restrict__ gammap, const float* __restrict__ x,
    float* __restrict__ out)
{
    __shared__ __align__(16) char lds[CONV_LDS];
    const int b   = blockIdx.y;
    const int h0  = blockIdx.x * 2;
    const int tid = threadIdx.x;
    const int wid = tid >> 6;
    const int lane = tid & 63;
    const int l15 = lane & 15;
    const int lj  = lane >> 4;
    const int wn  = wid & 1;
    const int wc  = wid >> 1;

    const char* psrc = (const char*)(AOT + (size_t)b*AOT_IMGE + (size_t)h0*AOT_ROWE);
    for (int i = tid; i < PATCH_SZ/16; i += 512)
        async_copy16(lds + i*16, psrc + i*16);
    for (int i = tid; i < WSLAB/16; i += 512)
        async_copy16(lds + PATCH_SZ + i*16, (const char*)Wt + i*16);
    __syncthreads();

    f32x4 acc[4][8];
    #pragma unroll
    for (int cf = 0; cf < 4; ++cf)
        #pragma unroll
        for (int nf = 0; nf < 8; ++nf)
            acc[cf][nf] = (f32x4){0.f, 0.f, 0.f, 0.f};

    for (int kk = 0; kk < 9; ++kk) {
        if (kk < 8) {
            const char* wsrc = (const char*)Wt + (size_t)(kk+1)*WSLAB;
            char* wdst = lds + PATCH_SZ + ((kk+1)&1)*WSLAB;
            for (int i = tid; i < WSLAB/16; i += 512)
                async_copy16(wdst + i*16, wsrc + i*16);
        }
        const int kh = kk / 3, kw = kk % 3;
        const char* wbase = lds + PATCH_SZ + (kk&1)*WSLAB;
        bf16x8 af[4];
        #pragma unroll
        for (int cf = 0; cf < 4; ++cf)
            af[cf] = ld_frag8(wbase + (wc*64 + cf*16 + l15)*88 + lj*16);
        #pragma unroll
        for (int nf = 0; nf < 8; ++nf) {
            const int cell = (wn + kh)*130 + nf*16 + l15 + kw;
            const bf16x8 bfr = ld_frag8(lds + cell*88 + lj*16);
            #pragma unroll
            for (int cf = 0; cf < 4; ++cf)
                acc[cf][nf] = __builtin_amdgcn_mfma_f32_16x16x32_bf16(
                    af[cf], bfr, acc[cf][nf], 0, 0, 0);
        }
        __syncthreads();
    }

    const float g0 = gammap[0];
    float* lf = (float*)lds;
    for (int k = 0; k < 4; ++k) {
        if (wc == k) {
            #pragma unroll
            for (int cf = 0; cf < 4; ++cf) {
                const int rl = cf*16 + 4*lj;
                #pragma unroll
                for (int nf = 0; nf < 8; ++nf) {
                    const int col = wn*128 + nf*16 + l15;
                    #pragma unroll
                    for (int j = 0; j < 4; ++j)
                        lf[(rl + j)*EPI_PITCH + col] = acc[cf][nf][j];
                }
            }
        }
        __syncthreads();
        #pragma unroll
        for (int it = 0; it < 8; ++it) {
            const int idx = tid + it*512;
            const int row = idx >> 6, c4 = idx & 63;
            const int co  = k*64 + row;
            const size_t g = ((size_t)b*CC + co)*NN + (size_t)h0*WW + c4*4;
            float4 v  = *(const float4*)(lf + row*EPI_PITCH + c4*4);
            float4 xv = *(const float4*)(x + g);
            float4 o;
            o.x = g0*gelu_fast(v.x) + xv.x;
            o.y = g0*gelu_fast(v.y) + xv.y;
            o.z = g0*gelu_fast(v.z) + xv.z;
            o.w = g0*gelu_fast(v.w) + xv.w;
            *(float4*)(out + g) = o;
        }
        __syncthreads();
    }
}

// ---------------------------------------------------------------------------
extern "C" void kernel_launch(void* const* d_in, const int* in_sizes, int n_in,
                              void* d_out, int out_size, void* d_ws, size_t ws_size,
                              hipStream_t stream)
{
    const float* x  = (const float*)d_in[0];
    const float* wq = (const float*)d_in[1];
    const float* bq = (const float*)d_in[2];
    const float* wk = (const float*)d_in[3];
    const float* bk = (const float*)d_in[4];
    const float* wv = (const float*)d_in[5];
    const float* bv = (const float*)d_in[6];
    const float* wp = (const float*)d_in[7];
    const float* gm = (const float*)d_in[8];
    float* out = (float*)d_out;

    // V scratch aliased into d_out (pv reads it before conv overwrites out).
    float* Vbuf = out;

    char* ws = (char*)d_ws;
    unsigned short* AOT  = (unsigned short*)ws;
    unsigned short* Wt   = (unsigned short*)(ws + AOT_ALLOC);
    unsigned short* Aswz = (unsigned short*)(ws + AOT_ALLOC + WT_BYTES);
    float* Ep  = (float*)(ws + AOT_ALLOC + WT_BYTES + ASWZ_BYTES);  // 8 MB
    float* Epr = Ep + (size_t)512*BB*1024;                          // 1 MB
    float* ATT = Epr + (size_t)64*BB*1024;

    prep_kernel    <<<dim3(1024), 256, 0, stream>>>(wp, Wt, wq, wk, wv, Aswz, AOT);
    qkv_mfma_kernel<<<dim3(512, BB), 256, 0, stream>>>(x, Aswz, bq, bk, bv, Vbuf, Ep);
    ereduce_kernel <<<dim3(64, BB), 256, 0, stream>>>(Ep, Epr);
    softmax_kernel <<<dim3(BB), dim3(32, 32), 0, stream>>>(Epr, ATT);
    pv_kernel      <<<dim3(128, BB), 256, 0, stream>>>(Vbuf, ATT, AOT);
    conv_kernel    <<<dim3(64, BB), 512, 0, stream>>>(AOT, Wt, gm, x, out);
}

// Round 10
// 81.073 us; speedup vs baseline: 1.0911x; 1.0283x over previous
//
#include <hip/hip_runtime.h>
#include <hip/hip_bf16.h>
#include <math.h>

#define BB 4
#define CC 256
#define HH 128
#define WW 128
#define NN (HH*WW)
#define DD 32

// AOT: attention output, bf16, spatially padded +1 border, ci padded 32->44.
#define AOT_CI   44
#define AOT_ROWE (130*AOT_CI)                  // shorts per padded row (5720)
#define AOT_IMGE (130*AOT_ROWE)                // shorts per batch (743600)
#define AOT_BYTES ((size_t)BB*AOT_IMGE*2)      // 5,948,800
#define AOT_ALLOC (AOT_BYTES + 1024)

#define WT_BYTES (9*256*AOT_CI*2)              // 202,752

// conv LDS geometry (2-row tile)
#define PATCH_SZ 45760                         // 4 padded rows * 130 * 88
#define WSLAB    22528                         // 256 co * 88
#define CONV_LDS (PATCH_SZ + 2*WSLAB)          // 90,816
#define EPI_PITCH 260

// qkv: A pre-swizzled [32 kstep][3 cf][64 lane][8 bf16] = 96 KB (L2-resident)
#define ASWZ_BYTES 98304
#define QKP5 68                                // qk tile row pitch (floats)

typedef __attribute__((ext_vector_type(8)))  short bf16x8;
typedef __attribute__((ext_vector_type(4)))  float f32x4;
typedef __attribute__((ext_vector_type(16))) float f32x16;

__device__ inline void async_copy16(void* lds, const void* g) {
    __builtin_amdgcn_global_load_lds(
        (const __attribute__((address_space(1))) unsigned int*)g,
        (__attribute__((address_space(3))) unsigned int*)lds, 16, 0, 0);
}

__device__ inline unsigned short f2bf(float f) {
    __hip_bfloat16 h = __float2bfloat16(f);
    return *reinterpret_cast<unsigned short*>(&h);
}

__device__ inline void split2(float v, unsigned short& h, unsigned short& l) {
    __hip_bfloat16 hb = __float2bfloat16(v);
    float r = v - __bfloat162float(hb);     // exact (Sterbenz)
    __hip_bfloat16 lb = __float2bfloat16(r);
    h = *reinterpret_cast<unsigned short*>(&hb);
    l = *reinterpret_cast<unsigned short*>(&lb);
}

// truncation split packed: low16 = bf16(hi), high16 = bf16(lo residual)
__device__ inline unsigned int packsplit(float v) {
    unsigned int fb = __float_as_uint(v);
    unsigned int hb = fb & 0xFFFF0000u;
    float r = v - __uint_as_float(hb);
    unsigned int lb = __float_as_uint(r) >> 16;
    return (hb >> 16) | (lb << 16);
}

// 8B+8B LDS load of a bf16x8 fragment (88B row pitch is only 8B-aligned)
__device__ inline bf16x8 ld_frag8(const char* p) {
    union { bf16x8 v; short4 h[2]; } u;
    u.h[0] = *(const short4*)(p);
    u.h[1] = *(const short4*)(p + 8);
    return u.v;
}

// A&S 7.1.26 erf approximation, |err| ~1e-6
__device__ inline float gelu_fast(float v) {
    float a = fabsf(v) * 0.70710678118654752f;
    float t = __fdividef(1.0f, fmaf(0.3275911f, a, 1.0f));
    float p = t * fmaf(t, fmaf(t, fmaf(t, fmaf(t, 1.061405429f, -1.453152027f),
                                       1.421413741f), -0.284496736f), 0.254829592f);
    float e = 1.0f - p * __expf(-a * a);
    float erfv = (v < 0.0f) ? -e : e;
    return 0.5f * v * (1.0f + erfv);
}

// ---------------------------------------------------------------------------
// K0: fused prep — conv weight repack | qkv A-pack | AOT border zero.
// ---------------------------------------------------------------------------
__global__ __launch_bounds__(256) void prep_kernel(
    const float* __restrict__ wp, unsigned short* __restrict__ Wt,
    const float* __restrict__ wq, const float* __restrict__ wk,
    const float* __restrict__ wv, unsigned short* __restrict__ Aswz,
    unsigned short* __restrict__ AOT)
{
    const int blk = blockIdx.x;
    if (blk < 288) {                       // conv weights: 9*256*32 = 73728
        int i = blk*256 + threadIdx.x;
        int kk = i / (256*32);
        int r  = i % (256*32);
        int co = r >> 5, ci = r & 31;
        float v = wp[((size_t)co*32 + ci)*9 + kk];
        Wt[((size_t)kk*256 + co)*AOT_CI + ci] = f2bf(v);
    } else if (blk < 480) {                // qkv A image: 49152 entries
        int i = (blk-288)*256 + threadIdx.x;
        int j    = i & 7;
        int lane = (i >> 3) & 63;
        int cf   = (i >> 9) % 3;
        int s    = i / 1536;
        int row  = cf*32 + (lane & 31);
        int k    = s*16 + (lane >> 5)*8 + j;
        int c    = k >> 1;
        float w  = (row < 32) ? wq[row*256 + c]
                 : (row < 64) ? wk[(row-32)*256 + c]
                              : wv[(row-64)*256 + c];
        unsigned short h, l;
        split2(w, h, l);
        Aswz[i] = (k & 1) ? l : h;
    } else {                               // AOT border zero: 4*22704 shorts
        int idx = (blk-480)*256 + threadIdx.x;
        if (idx < BB*22704) {
            int b = idx / 22704;
            int r = idx % 22704;
            size_t off;
            if (r < 11440) {
                int row = (r < 5720) ? 0 : 129;
                int e   = (r < 5720) ? r : r - 5720;
                off = (size_t)b*AOT_IMGE + (size_t)row*AOT_ROWE + e;
            } else {
                int r2 = r - 11440;
                int rr = r2 / 88 + 1;
                int w2 = r2 % 88;
                int col = (w2 < 44) ? 0 : 129;
                int ci  = (w2 < 44) ? w2 : w2 - 44;
                off = (size_t)b*AOT_IMGE + (size_t)rr*AOT_ROWE
                    + (size_t)col*AOT_CI + ci;
            }
            AOT[off] = 0;
        }
    }
}

// ---------------------------------------------------------------------------
// K1: QKV MFMA GEMM v5 — float4 x loads (G13 fix), LDS split-pair staging.
// grid (256 n-tiles of 64, B), 256 thr = 4 waves = (2 n-subtiles x 2 K-halves).
// Per round r (2 rounds): stage 2 chunks (64ch x 64n, uint = packed hi|lo
// bf16) via float4 global loads; wave (wn,wk) computes 8 k-steps on its
// chunk: B-frag = 4 conflict-free ds_read_b32 + dup-hi / dup-lo passes
// (exact 4-term split product); A-frags per-lane from global (L2, depth-2).
// Epilogue: 2-slab K-reduce, Q,K(+bias) -> qk LDS tile, V(+bias) -> global,
// energy partial E[32][32] over 64 n -> Ep (256 partial sets per b).
// ---------------------------------------------------------------------------
__global__ __launch_bounds__(256, 3) void qkv_mfma_kernel(
    const float* __restrict__ x, const unsigned short* __restrict__ Aswz,
    const float* __restrict__ bq, const float* __restrict__ bk,
    const float* __restrict__ bv,
    float* __restrict__ Vout, float* __restrict__ Ep)
{
    __shared__ __align__(16) float lds_f[8192 + 96];     // stage/qk + bias
    const int b    = blockIdx.y;
    const int s    = blockIdx.x;                 // 0..255
    const int n0   = s * 64;
    const int tid  = threadIdx.x;
    const int w    = tid >> 6;
    const int lane = tid & 63;
    const int l31  = lane & 31;
    const int lh   = lane >> 5;
    const int wn   = w & 1;                      // n-subtile
    const int wk   = w >> 1;                     // K-half

    float* biasL = lds_f + 8192;
    if (tid < 96)
        biasL[tid] = (tid < 32) ? bq[tid] : (tid < 64) ? bk[tid-32] : bv[tid-64];

    unsigned int* stage = (unsigned int*)lds_f;
    const bf16x8* Ab = (const bf16x8*)Aswz;

    f32x16 acc0 = {0}, acc1 = {0}, acc2 = {0};

    for (int r = 0; r < 2; ++r) {
        if (r) __syncthreads();                  // prior round's reads done
        // ---- stage: 8 float4 per thread, split-pack, ds_write_b128 ----
        #pragma unroll
        for (int i = 0; i < 8; ++i) {
            const int idx  = i*256 + tid;
            const int cidx = idx >> 10;          // which K-half chunk
            const int rem  = idx & 1023;
            const int chl  = rem >> 4;           // 0..63
            const int f4   = rem & 15;           // n-quad
            const float4 v4 = *(const float4*)(
                x + ((size_t)b*CC + cidx*128 + r*64 + chl)*NN + n0 + f4*4);
            uint4 u;
            u.x = packsplit(v4.x); u.y = packsplit(v4.y);
            u.z = packsplit(v4.z); u.w = packsplit(v4.w);
            *(uint4*)(stage + cidx*4096 + chl*64 + f4*4) = u;
        }
        __syncthreads();
        // ---- compute 8 k-steps on this wave's chunk ----
        bf16x8 aq[2][3];
        {
            const int sg0 = wk*16 + r*8;
            #pragma unroll
            for (int p = 0; p < 2; ++p) {
                aq[p][0] = Ab[((sg0+p)*3 + 0)*64 + lane];
                aq[p][1] = Ab[((sg0+p)*3 + 1)*64 + lane];
                aq[p][2] = Ab[((sg0+p)*3 + 2)*64 + lane];
            }
        }
        #pragma unroll
        for (int st = 0; st < 8; ++st) {
            const int st_g = wk*16 + r*8 + st;
            bf16x8 a0 = aq[st & 1][0];
            bf16x8 a1 = aq[st & 1][1];
            bf16x8 a2 = aq[st & 1][2];
            if (st < 6) {
                aq[st & 1][0] = Ab[((st_g+2)*3 + 0)*64 + lane];
                aq[st & 1][1] = Ab[((st_g+2)*3 + 1)*64 + lane];
                aq[st & 1][2] = Ab[((st_g+2)*3 + 2)*64 + lane];
            }
            unsigned int u0 = stage[wk*4096 + (8*st + 4*lh + 0)*64 + 32*wn + l31];
            unsigned int u1 = stage[wk*4096 + (8*st + 4*lh + 1)*64 + 32*wn + l31];
            unsigned int u2 = stage[wk*4096 + (8*st + 4*lh + 2)*64 + 32*wn + l31];
            unsigned int u3 = stage[wk*4096 + (8*st + 4*lh + 3)*64 + 32*wn + l31];
            union { bf16x8 v; unsigned int d[4]; } B1, B2;
            B1.d[0] = (u0 << 16) | (u0 & 0xFFFFu);
            B1.d[1] = (u1 << 16) | (u1 & 0xFFFFu);
            B1.d[2] = (u2 << 16) | (u2 & 0xFFFFu);
            B1.d[3] = (u3 << 16) | (u3 & 0xFFFFu);
            B2.d[0] = (u0 & 0xFFFF0000u) | (u0 >> 16);
            B2.d[1] = (u1 & 0xFFFF0000u) | (u1 >> 16);
            B2.d[2] = (u2 & 0xFFFF0000u) | (u2 >> 16);
            B2.d[3] = (u3 & 0xFFFF0000u) | (u3 >> 16);
            acc0 = __builtin_amdgcn_mfma_f32_32x32x16_bf16(a0, B1.v, acc0, 0, 0, 0);
            acc1 = __builtin_amdgcn_mfma_f32_32x32x16_bf16(a1, B1.v, acc1, 0, 0, 0);
            acc2 = __builtin_amdgcn_mfma_f32_32x32x16_bf16(a2, B1.v, acc2, 0, 0, 0);
            acc0 = __builtin_amdgcn_mfma_f32_32x32x16_bf16(a0, B2.v, acc0, 0, 0, 0);
            acc1 = __builtin_amdgcn_mfma_f32_32x32x16_bf16(a1, B2.v, acc1, 0, 0, 0);
            acc2 = __builtin_amdgcn_mfma_f32_32x32x16_bf16(a2, B2.v, acc2, 0, 0, 0);
        }
    }

    // ---- K-reduce across wk pairs via LDS slabs ----
    __syncthreads();
    if (wk == 1) {
        float* slab = lds_f + wn*3072;
        #pragma unroll
        for (int r = 0; r < 16; ++r) {
            slab[(     r)*64 + lane] = acc0[r];
            slab[(16 + r)*64 + lane] = acc1[r];
            slab[(32 + r)*64 + lane] = acc2[r];
        }
    }
    __syncthreads();
    float sq[16], sk[16], sv[16];
    if (wk == 0) {
        const float* slab = lds_f + wn*3072;
        #pragma unroll
        for (int r = 0; r < 16; ++r) {
            const int rsub = (r & 3) + 8*(r >> 2) + 4*lh;
            sq[r] = acc0[r] + slab[(     r)*64 + lane] + biasL[rsub];
            sk[r] = acc1[r] + slab[(16 + r)*64 + lane] + biasL[32 + rsub];
            sv[r] = acc2[r] + slab[(32 + r)*64 + lane] + biasL[64 + rsub];
        }
    }
    __syncthreads();                     // slabs consumed; qk area free
    if (wk == 0) {
        #pragma unroll
        for (int r = 0; r < 16; ++r) {
            const int rsub = (r & 3) + 8*(r >> 2) + 4*lh;
            lds_f[rsub*QKP5      + 32*wn + l31] = sq[r];
            lds_f[(32+rsub)*QKP5 + 32*wn + l31] = sk[r];
            Vout[((size_t)b*DD + rsub)*NN + n0 + 32*wn + l31] = sv[r];
        }
    }
    __syncthreads();

    // ---- energy partial: E[d][e] = sum_n Q[d][n]*K[e][n] over 64 n ----
    const int d  = tid >> 3;                    // 0..31
    const int e0 = tid & 7;
    const float* qrow = lds_f + d*QKP5;
    float s0 = 0.f, s1 = 0.f, s2 = 0.f, s3 = 0.f;
    #pragma unroll
    for (int n4 = 0; n4 < 64; n4 += 4) {
        float4 qv = *(const float4*)(qrow + n4);
        float4 k0 = *(const float4*)(lds_f + (32 + e0     )*QKP5 + n4);
        float4 k1 = *(const float4*)(lds_f + (32 + e0 +  8)*QKP5 + n4);
        float4 k2 = *(const float4*)(lds_f + (32 + e0 + 16)*QKP5 + n4);
        float4 k3 = *(const float4*)(lds_f + (32 + e0 + 24)*QKP5 + n4);
        s0 += qv.x*k0.x + qv.y*k0.y + qv.z*k0.z + qv.w*k0.w;
        s1 += qv.x*k1.x + qv.y*k1.y + qv.z*k1.z + qv.w*k1.w;
        s2 += qv.x*k2.x + qv.y*k2.y + qv.z*k2.z + qv.w*k2.w;
        s3 += qv.x*k3.x + qv.y*k3.y + qv.z*k3.z + qv.w*k3.w;
    }
    float* ep = Ep + ((size_t)s*BB + b)*1024;
    ep[d*32 + e0]      = s0;
    ep[d*32 + e0 + 8]  = s1;
    ep[d*32 + e0 + 16] = s2;
    ep[d*32 + e0 + 24] = s3;
}

// ---------------------------------------------------------------------------
// K2: fold 256 energy partials -> 32 (8:1), float4 per thread.
// ---------------------------------------------------------------------------
__global__ __launch_bounds__(256) void ereduce_kernel(
    const float* __restrict__ Ep, float* __restrict__ Epr)
{
    const int b = blockIdx.y, S = blockIdx.x;   // S: 0..31
    const int t = threadIdx.x;
    float4 a = {0.f, 0.f, 0.f, 0.f};
    #pragma unroll
    for (int p = 0; p < 8; ++p) {
        float4 v = *(const float4*)(Ep + ((size_t)(S*8 + p)*BB + b)*1024 + t*4);
        a.x += v.x; a.y += v.y; a.z += v.z; a.w += v.w;
    }
    *(float4*)(Epr + ((size_t)S*BB + b)*1024 + t*4) = a;
}

// ---------------------------------------------------------------------------
// K3: softmax over 32 partials.  softmax(max-E)==softmax(-E).
// ---------------------------------------------------------------------------
__global__ __launch_bounds__(1024) void softmax_kernel(
    const float* __restrict__ Ep, float* __restrict__ attT)
{
    const int b = blockIdx.x;
    const int e = threadIdx.x, d = threadIdx.y;
    float s = 0.f;
    #pragma unroll
    for (int p = 0; p < 32; ++p)
        s += Ep[((size_t)p * BB + b) * (DD * DD) + d * DD + e];
    float nv = -s;
    float m = nv;
    for (int off = 16; off > 0; off >>= 1) m = fmaxf(m, __shfl_xor(m, off, 32));
    float pe = expf(nv - m);
    float su = pe;
    for (int off = 16; off > 0; off >>= 1) su += __shfl_xor(su, off, 32);
    attT[(size_t)b * (DD * DD) + e * DD + d] = pe / su;
}

// ---------------------------------------------------------------------------
// K4: PV — reads standalone V[b][32][N]; writes bf16 AOT padded layout.
// ---------------------------------------------------------------------------
__global__ __launch_bounds__(256) void pv_kernel(
    const float* __restrict__ V, const float* __restrict__ attT,
    unsigned short* __restrict__ AOT)
{
    __shared__ float Vs[DD][128];
    __shared__ float at4[DD][DD];        // [e][d]
    const int b  = blockIdx.y;
    const int n0 = blockIdx.x * 128;
    const int tid = threadIdx.x;
    for (int i = tid; i < 1024; i += 256) {
        int r = i >> 5, c4 = i & 31;
        *(float4*)&Vs[r][c4*4] =
            *(const float4*)(V + ((size_t)b*DD + r)*NN + n0 + c4*4);
    }
    for (int i = tid; i < 1024; i += 256)
        at4[i >> 5][i & 31] = attT[(size_t)b*1024 + i];
    __syncthreads();
    const int nl = tid & 127;
    const int dg = tid >> 7;
    float acc[16];
    #pragma unroll
    for (int k = 0; k < 16; ++k) acc[k] = 0.f;
    #pragma unroll 4
    for (int e = 0; e < DD; ++e) {
        float v = Vs[e][nl];
        const float4* ar = (const float4*)&at4[e][dg*16];
        #pragma unroll
        for (int q = 0; q < 4; ++q) {
            float4 a = ar[q];
            acc[4*q+0] += a.x * v; acc[4*q+1] += a.y * v;
            acc[4*q+2] += a.z * v; acc[4*q+3] += a.w * v;
        }
    }
    const int n = n0 + nl;
    const int h = n >> 7, ww = n & 127;
    unsigned short* dst = AOT + (size_t)b*AOT_IMGE + (size_t)(h+1)*AOT_ROWE
                              + (size_t)(ww+1)*AOT_CI + dg*16;
    #pragma unroll
    for (int q = 0; q < 4; ++q) {
        ushort4 u;
        u.x = f2bf(acc[4*q+0]); u.y = f2bf(acc[4*q+1]);
        u.z = f2bf(acc[4*q+2]); u.w = f2bf(acc[4*q+3]);
        *(ushort4*)(dst + 4*q) = u;
    }
}

// ---------------------------------------------------------------------------
// K5: conv implicit-GEMM, 2 H-rows per block (unchanged).
// ---------------------------------------------------------------------------
__global__ __launch_bounds__(512, 1) void conv_kernel(
    const unsigned short* __restrict__ AOT, const unsigned short* __restrict__ Wt,
    const float* __restrict__ gammap, const float* __restrict__ x,
    float* __restrict__ out)
{
    __shared__ __align__(16) char lds[CONV_LDS];
    const int b   = blockIdx.y;
    const int h0  = blockIdx.x * 2;
    const int tid = threadIdx.x;
    const int wid = tid >> 6;
    const int lane = tid & 63;
    const int l15 = lane & 15;
    const int lj  = lane >> 4;
    const int wn  = wid & 1;
    const int wc  = wid >> 1;

    const char* psrc = (const char*)(AOT + (size_t)b*AOT_IMGE + (size_t)h0*AOT_ROWE);
    for (int i = tid; i < PATCH_SZ/16; i += 512)
        async_copy16(lds + i*16, psrc + i*16);
    for (int i = tid; i < WSLAB/16; i += 512)
        async_copy16(lds + PATCH_SZ + i*16, (const char*)Wt + i*16);
    __syncthreads();

    f32x4 acc[4][8];
    #pragma unroll
    for (int cf = 0; cf < 4; ++cf)
        #pragma unroll
        for (int nf = 0; nf < 8; ++nf)
            acc[cf][nf] = (f32x4){0.f, 0.f, 0.f, 0.f};

    for (int kk = 0; kk < 9; ++kk) {
        if (kk < 8) {
            const char* wsrc = (const char*)Wt + (size_t)(kk+1)*WSLAB;
            char* wdst = lds + PATCH_SZ + ((kk+1)&1)*WSLAB;
            for (int i = tid; i < WSLAB/16; i += 512)
                async_copy16(wdst + i*16, wsrc + i*16);
        }
        const int kh = kk / 3, kw = kk % 3;
        const char* wbase = lds + PATCH_SZ + (kk&1)*WSLAB;
        bf16x8 af[4];
        #pragma unroll
        for (int cf = 0; cf < 4; ++cf)
            af[cf] = ld_frag8(wbase + (wc*64 + cf*16 + l15)*88 + lj*16);
        #pragma unroll
        for (int nf = 0; nf < 8; ++nf) {
            const int cell = (wn + kh)*130 + nf*16 + l15 + kw;
            const bf16x8 bfr = ld_frag8(lds + cell*88 + lj*16);
            #pragma unroll
            for (int cf = 0; cf < 4; ++cf)
                acc[cf][nf] = __builtin_amdgcn_mfma_f32_16x16x32_bf16(
                    af[cf], bfr, acc[cf][nf], 0, 0, 0);
        }
        __syncthreads();
    }

    const float g0 = gammap[0];
    float* lf = (float*)lds;
    for (int k = 0; k < 4; ++k) {
        if (wc == k) {
            #pragma unroll
            for (int cf = 0; cf < 4; ++cf) {
                const int rl = cf*16 + 4*lj;
                #pragma unroll
                for (int nf = 0; nf < 8; ++nf) {
                    const int col = wn*128 + nf*16 + l15;
                    #pragma unroll
                    for (int j = 0; j < 4; ++j)
                        lf[(rl + j)*EPI_PITCH + col] = acc[cf][nf][j];
                }
            }
        }
        __syncthreads();
        #pragma unroll
        for (int it = 0; it < 8; ++it) {
            const int idx = tid + it*512;
            const int row = idx >> 6, c4 = idx & 63;
            const int co  = k*64 + row;
            const size_t g = ((size_t)b*CC + co)*NN + (size_t)h0*WW + c4*4;
            float4 v  = *(const float4*)(lf + row*EPI_PITCH + c4*4);
            float4 xv = *(const float4*)(x + g);
            float4 o;
            o.x = g0*gelu_fast(v.x) + xv.x;
            o.y = g0*gelu_fast(v.y) + xv.y;
            o.z = g0*gelu_fast(v.z) + xv.z;
            o.w = g0*gelu_fast(v.w) + xv.w;
            *(float4*)(out + g) = o;
        }
        __syncthreads();
    }
}

// ---------------------------------------------------------------------------
extern "C" void kernel_launch(void* const* d_in, const int* in_sizes, int n_in,
                              void* d_out, int out_size, void* d_ws, size_t ws_size,
                              hipStream_t stream)
{
    const float* x  = (const float*)d_in[0];
    const float* wq = (const float*)d_in[1];
    const float* bq = (const float*)d_in[2];
    const float* wk = (const float*)d_in[3];
    const float* bk = (const float*)d_in[4];
    const float* wv = (const float*)d_in[5];
    const float* bv = (const float*)d_in[6];
    const float* wp = (const float*)d_in[7];
    const float* gm = (const float*)d_in[8];
    float* out = (float*)d_out;

    // V scratch aliased into d_out (pv reads it before conv overwrites out).
    float* Vbuf = out;

    char* ws = (char*)d_ws;
    unsigned short* AOT  = (unsigned short*)ws;
    unsigned short* Wt   = (unsigned short*)(ws + AOT_ALLOC);
    unsigned short* Aswz = (unsigned short*)(ws + AOT_ALLOC + WT_BYTES);
    float* Ep  = (float*)(ws + AOT_ALLOC + WT_BYTES + ASWZ_BYTES);  // 4 MB
    float* Epr = Ep + (size_t)256*BB*1024;                          // 512 KB
    float* ATT = Epr + (size_t)32*BB*1024;

    prep_kernel    <<<dim3(1024), 256, 0, stream>>>(wp, Wt, wq, wk, wv, Aswz, AOT);
    qkv_mfma_kernel<<<dim3(256, BB), 256, 0, stream>>>(x, Aswz, bq, bk, bv, Vbuf, Ep);
    ereduce_kernel <<<dim3(32, BB), 256, 0, stream>>>(Ep, Epr);
    softmax_kernel <<<dim3(BB), dim3(32, 32), 0, stream>>>(Epr, ATT);
    pv_kernel      <<<dim3(128, BB), 256, 0, stream>>>(Vbuf, ATT, AOT);
    conv_kernel    <<<dim3(64, BB), 512, 0, stream>>>(AOT, Wt, gm, x, out);
}

// Round 11
// 79.891 us; speedup vs baseline: 1.1072x; 1.0148x over previous
//
#include <hip/hip_runtime.h>
#include <hip/hip_bf16.h>
#include <math.h>

#define BB 4
#define CC 256
#define HH 128
#define WW 128
#define NN (HH*WW)
#define DD 32

// AOT: attention output, bf16, spatially padded +1 border, ci padded 32->44.
#define AOT_CI   44
#define AOT_ROWE (130*AOT_CI)                  // shorts per padded row (5720)
#define AOT_IMGE (130*AOT_ROWE)                // shorts per batch (743600)
#define AOT_BYTES ((size_t)BB*AOT_IMGE*2)      // 5,948,800
#define AOT_ALLOC (AOT_BYTES + 1024)

#define WT_BYTES (9*256*AOT_CI*2)              // 202,752

// conv LDS geometry (2-row tile)
#define PATCH_SZ 45760                         // 4 padded rows * 130 * 88
#define WSLAB    22528                         // 256 co * 88
#define CONV_LDS (PATCH_SZ + 2*WSLAB)          // 90,816
#define EPI_PITCH 260

// qkv: A image [16 kstep][hi/lo][3 cf][64 lane][16B] = 96 KB
#define ASWZ_BYTES 98304
#define QKVP 260                               // qk epilogue tile pitch (floats)
// qkv LDS map: A 0..98303 | stage bufs 98304 + k*16384 (2x16KB) | bias 131072
#define QKV_LDS 131584

typedef __attribute__((ext_vector_type(8)))  short bf16x8;
typedef __attribute__((ext_vector_type(4)))  float f32x4;
typedef __attribute__((ext_vector_type(16))) float f32x16;

__device__ inline void async_copy16(void* lds, const void* g) {
    __builtin_amdgcn_global_load_lds(
        (const __attribute__((address_space(1))) unsigned int*)g,
        (__attribute__((address_space(3))) unsigned int*)lds, 16, 0, 0);
}

__device__ inline unsigned short f2bf(float f) {
    __hip_bfloat16 h = __float2bfloat16(f);
    return *reinterpret_cast<unsigned short*>(&h);
}

__device__ inline void split2(float v, unsigned short& h, unsigned short& l) {
    __hip_bfloat16 hb = __float2bfloat16(v);
    float r = v - __bfloat162float(hb);     // exact (Sterbenz)
    __hip_bfloat16 lb = __float2bfloat16(r);
    h = *reinterpret_cast<unsigned short*>(&hb);
    l = *reinterpret_cast<unsigned short*>(&lb);
}

// truncation split packed: low16 = bf16(hi), high16 = bf16(lo residual)
__device__ inline unsigned int packsplit(float v) {
    unsigned int fb = __float_as_uint(v);
    unsigned int hb = fb & 0xFFFF0000u;
    float r = v - __uint_as_float(hb);
    unsigned int lb = __float_as_uint(r) >> 16;
    return (hb >> 16) | (lb << 16);
}

// 8B+8B LDS load of a bf16x8 fragment (88B row pitch is only 8B-aligned)
__device__ inline bf16x8 ld_frag8(const char* p) {
    union { bf16x8 v; short4 h[2]; } u;
    u.h[0] = *(const short4*)(p);
    u.h[1] = *(const short4*)(p + 8);
    return u.v;
}

// A&S 7.1.26 erf approximation, |err| ~1e-6
__device__ inline float gelu_fast(float v) {
    float a = fabsf(v) * 0.70710678118654752f;
    float t = __fdividef(1.0f, fmaf(0.3275911f, a, 1.0f));
    float p = t * fmaf(t, fmaf(t, fmaf(t, fmaf(t, 1.061405429f, -1.453152027f),
                                       1.421413741f), -0.284496736f), 0.254829592f);
    float e = 1.0f - p * __expf(-a * a);
    float erfv = (v < 0.0f) ? -e : e;
    return 0.5f * v * (1.0f + erfv);
}

// ---------------------------------------------------------------------------
// K0: fused prep — conv weight repack | qkv A-pack (new layout) | AOT border.
// ---------------------------------------------------------------------------
__global__ __launch_bounds__(256) void prep_kernel(
    const float* __restrict__ wp, unsigned short* __restrict__ Wt,
    const float* __restrict__ wq, const float* __restrict__ wk,
    const float* __restrict__ wv, unsigned short* __restrict__ Aswz,
    unsigned short* __restrict__ AOT)
{
    const int blk = blockIdx.x;
    if (blk < 288) {                       // conv weights: 9*256*32 = 73728
        int i = blk*256 + threadIdx.x;
        int kk = i / (256*32);
        int r  = i % (256*32);
        int co = r >> 5, ci = r & 31;
        float v = wp[((size_t)co*32 + ci)*9 + kk];
        Wt[((size_t)kk*256 + co)*AOT_CI + ci] = f2bf(v);
    } else if (blk < 480) {                // qkv A image: 49152 entries
        int i = (blk-288)*256 + threadIdx.x;
        int j    = i & 7;
        int lane = (i >> 3) & 63;
        int q9   = i >> 9;                 // (s*2+hl)*3 + cf, 0..95
        int cf   = q9 % 3;
        int t    = q9 / 3;
        int hl   = t & 1;
        int s    = t >> 1;                 // 0..15
        int row  = cf*32 + (lane & 31);
        int c    = s*16 + (lane >> 5)*8 + j;
        float w  = (row < 32) ? wq[row*256 + c]
                 : (row < 64) ? wk[(row-32)*256 + c]
                              : wv[(row-64)*256 + c];
        unsigned short h, l;
        split2(w, h, l);
        Aswz[i] = hl ? l : h;
    } else {                               // AOT border zero: 4*22704 shorts
        int idx = (blk-480)*256 + threadIdx.x;
        if (idx < BB*22704) {
            int b = idx / 22704;
            int r = idx % 22704;
            size_t off;
            if (r < 11440) {
                int row = (r < 5720) ? 0 : 129;
                int e   = (r < 5720) ? r : r - 5720;
                off = (size_t)b*AOT_IMGE + (size_t)row*AOT_ROWE + e;
            } else {
                int r2 = r - 11440;
                int rr = r2 / 88 + 1;
                int w2 = r2 % 88;
                int col = (w2 < 44) ? 0 : 129;
                int ci  = (w2 < 44) ? w2 : w2 - 44;
                off = (size_t)b*AOT_IMGE + (size_t)rr*AOT_ROWE
                    + (size_t)col*AOT_CI + ci;
            }
            AOT[off] = 0;
        }
    }
}

// ---------------------------------------------------------------------------
// K1: QKV MFMA GEMM v6 — 2-phase pipelined (T3/T14), LDS-shared split A.
// grid (64 n-tiles of 256, B), 512 thr = 8 waves; wave w owns n [32w,32w+32).
// A image (96 KB) staged once; 16 rounds of 16 channels: per round
//   compute(buf r) | pack+ds_write(r+1 -> other buf) | issue loads(r+3)
// with ONE barrier per round.  Per k-step (16 ch): B1=x_hi, B2=x_lo built
// from 8 ds_read_b32; acc += Ah*B1 + Ah*B2 + Al*B1 + Al*B2 (12 MFMA, exact
// 4-term split).  Epilogue: Q,K(+bias)->qk tile, V(+bias)->global, energy
// partial E[32][32] over 256 n -> Ep (64 partial sets).
// ---------------------------------------------------------------------------
__global__ __launch_bounds__(512, 1) void qkv_mfma_kernel(
    const float* __restrict__ x, const unsigned short* __restrict__ Aswz,
    const float* __restrict__ bq, const float* __restrict__ bk,
    const float* __restrict__ bv,
    float* __restrict__ Vout, float* __restrict__ Ep)
{
    __shared__ __align__(16) char lds[QKV_LDS];
    const int b    = blockIdx.y;
    const int s    = blockIdx.x;                 // 0..63
    const int n0   = s * 256;
    const int tid  = threadIdx.x;
    const int w    = tid >> 6;
    const int lane = tid & 63;
    const int l31  = lane & 31;
    const int lh   = lane >> 5;
    const int ch_a = tid >> 6;                   // 0..7
    const int f4   = tid & 63;                   // n-quad 0..63

    // stage A image (96 KB linear, 12 insts/thread)
    for (int i = tid; i < 6144; i += 512)
        async_copy16(lds + i*16, (const char*)Aswz + i*16);
    float* biasL = (float*)(lds + 131072);
    if (tid < 96)
        biasL[tid] = (tid < 32) ? bq[tid] : (tid < 64) ? bk[tid-32] : bv[tid-64];

    unsigned int* stg[2] = { (unsigned int*)(lds + 98304),
                             (unsigned int*)(lds + 114688) };
    const float* xb = x + (size_t)b*CC*NN + n0 + f4*4;

    f32x16 acc0 = {0}, acc1 = {0}, acc2 = {0};

    // 3 register sets for the load pipeline
    float4 va0, vb0, va1, vb1, va2, vb2;
    #define LOADX(VA, VB, R) do { \
        VA = *(const float4*)(xb + (size_t)((R)*16 + ch_a    )*NN); \
        VB = *(const float4*)(xb + (size_t)((R)*16 + ch_a + 8)*NN); } while (0)
    #define PACKW(BUF, VA, VB) do { \
        uint4 ua, ub; \
        ua.x = packsplit((VA).x); ua.y = packsplit((VA).y); \
        ua.z = packsplit((VA).z); ua.w = packsplit((VA).w); \
        ub.x = packsplit((VB).x); ub.y = packsplit((VB).y); \
        ub.z = packsplit((VB).z); ub.w = packsplit((VB).w); \
        *(uint4*)((BUF) + (ch_a    )*256 + f4*4) = ua; \
        *(uint4*)((BUF) + (ch_a + 8)*256 + f4*4) = ub; } while (0)

    LOADX(va0, vb0, 0);
    LOADX(va1, vb1, 1);
    LOADX(va2, vb2, 2);
    PACKW(stg[0], va0, vb0);
    __syncthreads();                             // A + buf0 resident

    #pragma unroll
    for (int r = 0; r < 16; ++r) {
        // ---- compute k-step r from buf[r&1] ----
        {
            const unsigned int* bufc = stg[r & 1];
            unsigned int u[8];
            #pragma unroll
            for (int j = 0; j < 8; ++j)
                u[j] = bufc[(lh*8 + j)*256 + 32*w + l31];
            union { bf16x8 v; unsigned int d[4]; } B1, B2;
            #pragma unroll
            for (int dq = 0; dq < 4; ++dq) {
                B1.d[dq] = (u[2*dq] & 0xFFFFu)      | (u[2*dq+1] << 16);
                B2.d[dq] = (u[2*dq] >> 16)          | (u[2*dq+1] & 0xFFFF0000u);
            }
            #pragma unroll
            for (int cf = 0; cf < 3; ++cf) {
                bf16x8 ah = *(const bf16x8*)(lds + (((r*6 +     cf)*64) + lane)*16);
                bf16x8 al = *(const bf16x8*)(lds + (((r*6 + 3 + cf)*64) + lane)*16);
                f32x16* ac = (cf == 0) ? &acc0 : (cf == 1) ? &acc1 : &acc2;
                *ac = __builtin_amdgcn_mfma_f32_32x32x16_bf16(ah, B1.v, *ac, 0, 0, 0);
                *ac = __builtin_amdgcn_mfma_f32_32x32x16_bf16(ah, B2.v, *ac, 0, 0, 0);
                *ac = __builtin_amdgcn_mfma_f32_32x32x16_bf16(al, B1.v, *ac, 0, 0, 0);
                *ac = __builtin_amdgcn_mfma_f32_32x32x16_bf16(al, B2.v, *ac, 0, 0, 0);
            }
        }
        // ---- pack+write round r+1 into the other buffer ----
        if (r < 15) {
            if ((r+1) % 3 == 0)      PACKW(stg[(r+1) & 1], va0, vb0);
            else if ((r+1) % 3 == 1) PACKW(stg[(r+1) & 1], va1, vb1);
            else                     PACKW(stg[(r+1) & 1], va2, vb2);
        }
        // ---- issue loads for round r+3 ----
        if (r + 3 < 16) {
            if ((r+3) % 3 == 0)      LOADX(va0, vb0, r+3);
            else if ((r+3) % 3 == 1) LOADX(va1, vb1, r+3);
            else                     LOADX(va2, vb2, r+3);
        }
        __syncthreads();
    }

    // ---- epilogue: Q,K -> qk tile (A region dead), V -> global ----
    float* qk = (float*)lds;
    #pragma unroll
    for (int r = 0; r < 16; ++r) {
        const int rsub = (r & 3) + 8*(r >> 2) + 4*lh;
        const int col  = 32*w + l31;
        qk[rsub*QKVP + col]      = acc0[r] + biasL[rsub];
        qk[(32+rsub)*QKVP + col] = acc1[r] + biasL[32 + rsub];
        Vout[((size_t)b*DD + rsub)*NN + n0 + col] = acc2[r] + biasL[64 + rsub];
    }
    __syncthreads();

    // ---- energy partial: E[d][e] = sum_n Q[d][n]*K[e][n] over 256 n ----
    const int d  = tid >> 4;                     // 0..31
    const int e2 = tid & 15;                     // handles e2 and e2+16
    const float* qrow = qk + d*QKVP;
    float s0 = 0.f, s1 = 0.f;
    for (int n4 = 0; n4 < 256; n4 += 4) {
        float4 qv = *(const float4*)(qrow + n4);
        float4 ka = *(const float4*)(qk + (32 + e2)*QKVP + n4);
        float4 kb = *(const float4*)(qk + (48 + e2)*QKVP + n4);
        s0 += qv.x*ka.x + qv.y*ka.y + qv.z*ka.z + qv.w*ka.w;
        s1 += qv.x*kb.x + qv.y*kb.y + qv.z*kb.z + qv.w*kb.w;
    }
    float* ep = Ep + ((size_t)s*BB + b)*1024;
    ep[d*32 + e2]      = s0;
    ep[d*32 + e2 + 16] = s1;
    #undef LOADX
    #undef PACKW
}

// ---------------------------------------------------------------------------
// K3: softmax over 64 partials.  softmax(max-E)==softmax(-E).
// ---------------------------------------------------------------------------
__global__ __launch_bounds__(1024) void softmax_kernel(
    const float* __restrict__ Ep, float* __restrict__ attT)
{
    const int b = blockIdx.x;
    const int e = threadIdx.x, d = threadIdx.y;
    float s = 0.f;
    #pragma unroll 8
    for (int p = 0; p < 64; ++p)
        s += Ep[((size_t)p * BB + b) * (DD * DD) + d * DD + e];
    float nv = -s;
    float m = nv;
    for (int off = 16; off > 0; off >>= 1) m = fmaxf(m, __shfl_xor(m, off, 32));
    float pe = expf(nv - m);
    float su = pe;
    for (int off = 16; off > 0; off >>= 1) su += __shfl_xor(su, off, 32);
    attT[(size_t)b * (DD * DD) + e * DD + d] = pe / su;
}

// ---------------------------------------------------------------------------
// K4: PV — reads standalone V[b][32][N]; writes bf16 AOT padded layout.
// ---------------------------------------------------------------------------
__global__ __launch_bounds__(256) void pv_kernel(
    const float* __restrict__ V, const float* __restrict__ attT,
    unsigned short* __restrict__ AOT)
{
    __shared__ float Vs[DD][128];
    __shared__ float at4[DD][DD];        // [e][d]
    const int b  = blockIdx.y;
    const int n0 = blockIdx.x * 128;
    const int tid = threadIdx.x;
    for (int i = tid; i < 1024; i += 256) {
        int r = i >> 5, c4 = i & 31;
        *(float4*)&Vs[r][c4*4] =
            *(const float4*)(V + ((size_t)b*DD + r)*NN + n0 + c4*4);
    }
    for (int i = tid; i < 1024; i += 256)
        at4[i >> 5][i & 31] = attT[(size_t)b*1024 + i];
    __syncthreads();
    const int nl = tid & 127;
    const int dg = tid >> 7;
    float acc[16];
    #pragma unroll
    for (int k = 0; k < 16; ++k) acc[k] = 0.f;
    #pragma unroll 4
    for (int e = 0; e < DD; ++e) {
        float v = Vs[e][nl];
        const float4* ar = (const float4*)&at4[e][dg*16];
        #pragma unroll
        for (int q = 0; q < 4; ++q) {
            float4 a = ar[q];
            acc[4*q+0] += a.x * v; acc[4*q+1] += a.y * v;
            acc[4*q+2] += a.z * v; acc[4*q+3] += a.w * v;
        }
    }
    const int n = n0 + nl;
    const int h = n >> 7, ww = n & 127;
    unsigned short* dst = AOT + (size_t)b*AOT_IMGE + (size_t)(h+1)*AOT_ROWE
                              + (size_t)(ww+1)*AOT_CI + dg*16;
    #pragma unroll
    for (int q = 0; q < 4; ++q) {
        ushort4 u;
        u.x = f2bf(acc[4*q+0]); u.y = f2bf(acc[4*q+1]);
        u.z = f2bf(acc[4*q+2]); u.w = f2bf(acc[4*q+3]);
        *(ushort4*)(dst + 4*q) = u;
    }
}

// ---------------------------------------------------------------------------
// K5: conv implicit-GEMM, 2 H-rows per block (unchanged).
// ---------------------------------------------------------------------------
__global__ __launch_bounds__(512, 1) void conv_kernel(
    const unsigned short* __restrict__ AOT, const unsigned short* __restrict__ Wt,
    const float* __restrict__ gammap, const float* __restrict__ x,
    float* __restrict__ out)
{
    __shared__ __align__(16) char lds[CONV_LDS];
    const int b   = blockIdx.y;
    const int h0  = blockIdx.x * 2;
    const int tid = threadIdx.x;
    const int wid = tid >> 6;
    const int lane = tid & 63;
    const int l15 = lane & 15;
    const int lj  = lane >> 4;
    const int wn  = wid & 1;
    const int wc  = wid >> 1;

    const char* psrc = (const char*)(AOT + (size_t)b*AOT_IMGE + (size_t)h0*AOT_ROWE);
    for (int i = tid; i < PATCH_SZ/16; i += 512)
        async_copy16(lds + i*16, psrc + i*16);
    for (int i = tid; i < WSLAB/16; i += 512)
        async_copy16(lds + PATCH_SZ + i*16, (const char*)Wt + i*16);
    __syncthreads();

    f32x4 acc[4][8];
    #pragma unroll
    for (int cf = 0; cf < 4; ++cf)
        #pragma unroll
        for (int nf = 0; nf < 8; ++nf)
            acc[cf][nf] = (f32x4){0.f, 0.f, 0.f, 0.f};

    for (int kk = 0; kk < 9; ++kk) {
        if (kk < 8) {
            const char* wsrc = (const char*)Wt + (size_t)(kk+1)*WSLAB;
            char* wdst = lds + PATCH_SZ + ((kk+1)&1)*WSLAB;
            for (int i = tid; i < WSLAB/16; i += 512)
                async_copy16(wdst + i*16, wsrc + i*16);
        }
        const int kh = kk / 3, kw = kk % 3;
        const char* wbase = lds + PATCH_SZ + (kk&1)*WSLAB;
        bf16x8 af[4];
        #pragma unroll
        for (int cf = 0; cf < 4; ++cf)
            af[cf] = ld_frag8(wbase + (wc*64 + cf*16 + l15)*88 + lj*16);
        #pragma unroll
        for (int nf = 0; nf < 8; ++nf) {
            const int cell = (wn + kh)*130 + nf*16 + l15 + kw;
            const bf16x8 bfr = ld_frag8(lds + cell*88 + lj*16);
            #pragma unroll
            for (int cf = 0; cf < 4; ++cf)
                acc[cf][nf] = __builtin_amdgcn_mfma_f32_16x16x32_bf16(
                    af[cf], bfr, acc[cf][nf], 0, 0, 0);
        }
        __syncthreads();
    }

    const float g0 = gammap[0];
    float* lf = (float*)lds;
    for (int k = 0; k < 4; ++k) {
        if (wc == k) {
            #pragma unroll
            for (int cf = 0; cf < 4; ++cf) {
                const int rl = cf*16 + 4*lj;
                #pragma unroll
                for (int nf = 0; nf < 8; ++nf) {
                    const int col = wn*128 + nf*16 + l15;
                    #pragma unroll
                    for (int j = 0; j < 4; ++j)
                        lf[(rl + j)*EPI_PITCH + col] = acc[cf][nf][j];
                }
            }
        }
        __syncthreads();
        #pragma unroll
        for (int it = 0; it < 8; ++it) {
            const int idx = tid + it*512;
            const int row = idx >> 6, c4 = idx & 63;
            const int co  = k*64 + row;
            const size_t g = ((size_t)b*CC + co)*NN + (size_t)h0*WW + c4*4;
            float4 v  = *(const float4*)(lf + row*EPI_PITCH + c4*4);
            float4 xv = *(const float4*)(x + g);
            float4 o;
            o.x = g0*gelu_fast(v.x) + xv.x;
            o.y = g0*gelu_fast(v.y) + xv.y;
            o.z = g0*gelu_fast(v.z) + xv.z;
            o.w = g0*gelu_fast(v.w) + xv.w;
            *(float4*)(out + g) = o;
        }
        __syncthreads();
    }
}

// ---------------------------------------------------------------------------
extern "C" void kernel_launch(void* const* d_in, const int* in_sizes, int n_in,
                              void* d_out, int out_size, void* d_ws, size_t ws_size,
                              hipStream_t stream)
{
    const float* x  = (const float*)d_in[0];
    const float* wq = (const float*)d_in[1];
    const float* bq = (const float*)d_in[2];
    const float* wk = (const float*)d_in[3];
    const float* bk = (const float*)d_in[4];
    const float* wv = (const float*)d_in[5];
    const float* bv = (const float*)d_in[6];
    const float* wp = (const float*)d_in[7];
    const float* gm = (const float*)d_in[8];
    float* out = (float*)d_out;

    // V scratch aliased into d_out (pv reads it before conv overwrites out).
    float* Vbuf = out;

    char* ws = (char*)d_ws;
    unsigned short* AOT  = (unsigned short*)ws;
    unsigned short* Wt   = (unsigned short*)(ws + AOT_ALLOC);
    unsigned short* Aswz = (unsigned short*)(ws + AOT_ALLOC + WT_BYTES);
    float* Ep  = (float*)(ws + AOT_ALLOC + WT_BYTES + ASWZ_BYTES);  // 1 MB
    float* ATT = Ep + (size_t)64*BB*1024;

    prep_kernel    <<<dim3(1024), 256, 0, stream>>>(wp, Wt, wq, wk, wv, Aswz, AOT);
    qkv_mfma_kernel<<<dim3(64, BB), 512, 0, stream>>>(x, Aswz, bq, bk, bv, Vbuf, Ep);
    softmax_kernel <<<dim3(BB), dim3(32, 32), 0, stream>>>(Ep, ATT);
    pv_kernel      <<<dim3(128, BB), 256, 0, stream>>>(Vbuf, ATT, AOT);
    conv_kernel    <<<dim3(64, BB), 512, 0, stream>>>(AOT, Wt, gm, x, out);
}